// Round 5
// baseline (359.610 us; speedup 1.0000x reference)
//
#include <hip/hip_runtime.h>
#include <hip/hip_bf16.h>

#define N_NODES 100000
#define N_EDGES 1600000
#define NFEAT 256
#define NHID 128
#define NCLASS 8

#define NCOPY 4
#define CAP 20                    // ELL slots per (node, copy); Poisson(4) tail ~1e-8
#define SLOTS (NCOPY * CAP)       // 80 slots per node, interleaved r*4+copy
#define OVCAP 8192                // overflow spill capacity (expected usage: 0)

// ---------------------------------------------------------------------------
// K1: fused degree histogram + ELL placement. 4 edges/thread (one per shadow
// copy). atomicAdd-with-return gives the slot index directly; interleaved
// layout ebuf[node*SLOTS + r*NCOPY + copy] keeps active slots line-dense.
__global__ __launch_bounds__(256) void degree_place_kernel(
        const int* __restrict__ esrc, const int* __restrict__ edst,
        int* __restrict__ degc, int* __restrict__ ebuf,
        int* __restrict__ ovcnt, int* __restrict__ ovbuf, int nE) {
    int e4 = (blockIdx.x * 256 + threadIdx.x) * 4;
    if (e4 >= nE) return;
    int4 s = *(const int4*)&esrc[e4];
    int4 d = *(const int4*)&edst[e4];
    int r0 = atomicAdd(&degc[0 * N_NODES + d.x], 1);
    int r1 = atomicAdd(&degc[1 * N_NODES + d.y], 1);
    int r2 = atomicAdd(&degc[2 * N_NODES + d.z], 1);
    int r3 = atomicAdd(&degc[3 * N_NODES + d.w], 1);
    if (r0 < CAP) ebuf[d.x * SLOTS + r0 * NCOPY + 0] = s.x;
    else { int p = atomicAdd(ovcnt, 1); if (p < OVCAP) { ovbuf[2*p] = s.x; ovbuf[2*p+1] = d.x; } }
    if (r1 < CAP) ebuf[d.y * SLOTS + r1 * NCOPY + 1] = s.y;
    else { int p = atomicAdd(ovcnt, 1); if (p < OVCAP) { ovbuf[2*p] = s.y; ovbuf[2*p+1] = d.y; } }
    if (r2 < CAP) ebuf[d.z * SLOTS + r2 * NCOPY + 2] = s.z;
    else { int p = atomicAdd(ovcnt, 1); if (p < OVCAP) { ovbuf[2*p] = s.z; ovbuf[2*p+1] = d.z; } }
    if (r3 < CAP) ebuf[d.w * SLOTS + r3 * NCOPY + 3] = s.w;
    else { int p = atomicAdd(ovcnt, 1); if (p < OVCAP) { ovbuf[2*p] = s.w; ovbuf[2*p+1] = d.w; } }
}

// ---------------------------------------------------------------------------
// K2: dinv = rsqrt(total_deg + 1); pack per-copy (capped) counts into one int.
__global__ __launch_bounds__(256) void dinv_pack_kernel(const int* __restrict__ degc,
                                                        float* __restrict__ dinv,
                                                        int* __restrict__ packed, int n) {
    int i = blockIdx.x * 256 + threadIdx.x;
    if (i >= n) return;
    int c0 = degc[i];
    int c1 = degc[n + i];
    int c2 = degc[2 * n + i];
    int c3 = degc[3 * n + i];
    dinv[i] = rsqrtf((float)(c0 + c1 + c2 + c3 + 1));
    c0 = min(c0, CAP); c1 = min(c1, CAP); c2 = min(c2, CAP); c3 = min(c3, CAP);
    packed[i] = c0 | (c1 << 8) | (c2 << 16) | (c3 << 24);
}

// ---------------------------------------------------------------------------
// Kc: WcT[8][256] = (W1 @ Wfc)^T  and  cvec[8] = b1 @ Wfc + bfc.
__global__ __launch_bounds__(256) void wc_kernel(const float* __restrict__ W1,
                                                 const float* __restrict__ b1,
                                                 const float* __restrict__ Wfc,
                                                 const float* __restrict__ bfc,
                                                 float* __restrict__ WcT,
                                                 float* __restrict__ cvec) {
    __shared__ float wfs[NHID * NCLASS];
    __shared__ float bs[NHID];
    int tid = threadIdx.x;
    for (int i = tid; i < NHID * NCLASS; i += 256) wfs[i] = Wfc[i];
    if (tid < NHID) bs[tid] = b1[tid];
    __syncthreads();

    float acc[NCLASS] = {};
    for (int h = 0; h < NHID; h++) {
        float w = W1[tid * NHID + h];
        #pragma unroll
        for (int c = 0; c < NCLASS; c++) acc[c] += w * wfs[h * NCLASS + c];
    }
    #pragma unroll
    for (int c = 0; c < NCLASS; c++) WcT[c * NFEAT + tid] = acc[c];

    if (tid < NCLASS) {
        float a = bfc[tid];
        for (int h = 0; h < NHID; h++) a += bs[h] * wfs[h * NCLASS + tid];
        cvec[tid] = a;
    }
}

// ---------------------------------------------------------------------------
// Kz: Zs[i][c] = dot(X[i], WcT[c]) * dinv[i].
// Wave = 8 rows; 8 lanes/row each own 32 features in 8 float4 regs (X read
// once, coalesced). WcT in LDS; per class 32 FMA + 3-step shfl_xor reduce.
__global__ __launch_bounds__(256) void z_kernel(const float* __restrict__ X,
                                                const float* __restrict__ WcT,
                                                const float* __restrict__ dinv,
                                                float* __restrict__ Zs, int n) {
    __shared__ float4 wlds[NCLASS * 64];
    int tid = threadIdx.x;
    #pragma unroll
    for (int i = tid; i < NCLASS * 64; i += 256)
        wlds[i] = ((const float4*)WcT)[i];
    __syncthreads();

    const int lane = tid & 63;
    const int sub  = lane & 7;
    const int rsub = lane >> 3;
    const int wid  = (blockIdx.x * 256 + tid) >> 6;
    const int nw   = (gridDim.x * 256) >> 6;
    const int ngroups = (n + 7) >> 3;

    for (int g = wid; g < ngroups; g += nw) {
        int row = g * 8 + rsub;
        bool ok = row < n;
        int r = ok ? row : (n - 1);
        const float4* xr = (const float4*)(X + (long)r * NFEAT);
        float4 xv[8];
        #pragma unroll
        for (int k = 0; k < 8; k++) xv[k] = xr[sub + 8 * k];

        float res = 0.f;
        #pragma unroll
        for (int c = 0; c < NCLASS; c++) {
            float s = 0.f;
            #pragma unroll
            for (int k = 0; k < 8; k++) {
                float4 w = wlds[c * 64 + sub + 8 * k];
                s += xv[k].x * w.x + xv[k].y * w.y + xv[k].z * w.z + xv[k].w * w.w;
            }
            s += __shfl_xor(s, 1);
            s += __shfl_xor(s, 2);
            s += __shfl_xor(s, 4);
            if (sub == c) res = s;
        }
        if (ok) Zs[(long)row * NCLASS + sub] = res * dinv[row];
    }
}

// ---------------------------------------------------------------------------
// Ko: apply overflow edges (normally zero) into Zov via atomics.
__global__ __launch_bounds__(256) void overflow_kernel(const int* __restrict__ ovcnt,
                                                       const int* __restrict__ ovbuf,
                                                       const float* __restrict__ Zs,
                                                       float* __restrict__ Zov) {
    int total = *ovcnt;
    if (total > OVCAP) total = OVCAP;
    for (int idx = blockIdx.x * 256 + threadIdx.x; idx < total * NCLASS;
         idx += gridDim.x * 256) {
        int e = idx >> 3, c = idx & 7;
        int s = ovbuf[2 * e], d = ovbuf[2 * e + 1];
        atomicAdd(&Zov[d * NCLASS + c], Zs[s * NCLASS + c]);
    }
}

// ---------------------------------------------------------------------------
// Kg: out[d] = dinv[d]*(Zs[d] + Zov[d] + sum_{s in ELL(d)} Zs[s]) + cvec
// Thread per (node, half-row): float4 granularity, 200k threads.
__global__ __launch_bounds__(256) void gather_fc_kernel(const float* __restrict__ Zs,
                                                        const int* __restrict__ ebuf,
                                                        const int* __restrict__ packed,
                                                        const float* __restrict__ dinv,
                                                        const float* __restrict__ Zov,
                                                        const float* __restrict__ cvec,
                                                        float* __restrict__ out, int n) {
    int idx = blockIdx.x * 256 + threadIdx.x;
    if (idx >= 2 * n) return;
    int node = idx >> 1;
    int h    = idx & 1;
    const float4* Zs4 = (const float4*)Zs;

    float4 a = Zs4[node * 2 + h];                       // self-loop (pre-scaled)
    float4 v = ((const float4*)Zov)[node * 2 + h];      // overflow contrib
    a.x += v.x; a.y += v.y; a.z += v.z; a.w += v.w;

    int pc = packed[node];
    const int* eb = ebuf + (long)node * SLOTS;

    #pragma unroll
    for (int copy = 0; copy < NCOPY; copy++) {
        int cnt = (pc >> (copy * 8)) & 255;
        int k = 0;
        for (; k + 1 < cnt; k += 2) {
            int s0 = eb[k * NCOPY + copy];
            int s1 = eb[(k + 1) * NCOPY + copy];
            float4 z0 = Zs4[s0 * 2 + h];
            float4 z1 = Zs4[s1 * 2 + h];
            a.x += z0.x + z1.x; a.y += z0.y + z1.y;
            a.z += z0.z + z1.z; a.w += z0.w + z1.w;
        }
        if (k < cnt) {
            float4 z = Zs4[eb[k * NCOPY + copy] * 2 + h];
            a.x += z.x; a.y += z.y; a.z += z.z; a.w += z.w;
        }
    }

    float dd = dinv[node];
    float4 cv = ((const float4*)cvec)[h];
    float4 o;
    o.x = a.x * dd + cv.x; o.y = a.y * dd + cv.y;
    o.z = a.z * dd + cv.z; o.w = a.w * dd + cv.w;
    ((float4*)out)[node * 2 + h] = o;
}

// ---------------------------------------------------------------------------
extern "C" void kernel_launch(void* const* d_in, const int* in_sizes, int n_in,
                              void* d_out, int out_size, void* d_ws, size_t ws_size,
                              hipStream_t stream) {
    const float* x    = (const float*)d_in[0];   // [N, 256]
    const int*   eidx = (const int*)d_in[1];     // [2, E]
    const float* W1   = (const float*)d_in[2];   // [256, 128]
    const float* b1   = (const float*)d_in[3];   // [128]
    const float* Wfc  = (const float*)d_in[4];   // [128, 8]
    const float* bfc  = (const float*)d_in[5];   // [8]
    float* out = (float*)d_out;

    const int N = N_NODES;
    const int E = in_sizes[1] / 2;

    const int* esrc = eidx;
    const int* edst = eidx + E;

    // workspace layout (~42 MB); all chunk sizes are multiples of 16 B.
    float* Zs     = (float*)d_ws;                    // 8N floats
    float* dinv   = Zs + (long)8 * N;                // N
    int*   packed = (int*)(dinv + N);                // N
    float* cvec   = (float*)(packed + N);            // 8
    float* WcT    = cvec + 8;                        // 8*256
    // ---- zeroed region start ----
    int*   degc   = (int*)(WcT + NCLASS * NFEAT);    // 4N
    int*   ovcnt  = degc + 4 * N;                    // 4 (padded)
    float* Zov    = (float*)(ovcnt + 4);             // 8N
    // ---- zeroed region end ----
    int*   ovbuf  = (int*)(Zov + (long)8 * N);       // 2*OVCAP
    int*   ebuf   = ovbuf + 2 * OVCAP;               // N*SLOTS (32 MB)

    size_t zero_bytes = (size_t)(4 * N + 4) * sizeof(int) + (size_t)8 * N * sizeof(float);
    hipMemsetAsync(degc, 0, zero_bytes, stream);

    wc_kernel<<<1, 256, 0, stream>>>(W1, b1, Wfc, bfc, WcT, cvec);

    degree_place_kernel<<<(E / 4 + 255) / 256, 256, 0, stream>>>(
        esrc, edst, degc, ebuf, ovcnt, ovbuf, E);

    dinv_pack_kernel<<<(N + 255) / 256, 256, 0, stream>>>(degc, dinv, packed, N);

    z_kernel<<<1563, 256, 0, stream>>>(x, WcT, dinv, Zs, N);

    overflow_kernel<<<4, 256, 0, stream>>>(ovcnt, ovbuf, Zs, Zov);

    gather_fc_kernel<<<(2 * N + 255) / 256, 256, 0, stream>>>(
        Zs, ebuf, packed, dinv, Zov, cvec, out, N);
}

// Round 6
// 260.908 us; speedup vs baseline: 1.3783x; 1.3783x over previous
//
#include <hip/hip_runtime.h>
#include <hip/hip_bf16.h>

#define N_NODES 100000
#define N_EDGES 1600000
#define NFEAT 256
#define NHID 128
#define NCLASS 8

#define NBLK 512                      // pass-A blocks
#define BSH 9                         // bucket = dst >> 9  (512 nodes/bucket)
#define NBUCK ((N_NODES + 511) >> 9)  // 196

// ---------------------------------------------------------------------------
// A1: per-block coarse histogram (196 buckets) via LDS atomics; atomic-free
// global write of the per-block histogram.
__global__ __launch_bounds__(256) void hist_kernel(const int* __restrict__ edst,
                                                   int* __restrict__ blockhist,
                                                   int chunk, int nE) {
    __shared__ int h[NBUCK];
    int tid = threadIdx.x;
    for (int i = tid; i < NBUCK; i += 256) h[i] = 0;
    __syncthreads();
    int e0 = blockIdx.x * chunk;
    int e1 = min(e0 + chunk, nE);
    for (int e = e0 + tid; e < e1; e += 256)
        atomicAdd(&h[edst[e] >> BSH], 1);            // LDS atomic
    __syncthreads();
    for (int i = tid; i < NBUCK; i += 256)
        blockhist[(long)blockIdx.x * NBUCK + i] = h[i];
}

// ---------------------------------------------------------------------------
// A2: for each bucket, exclusive scan over the 512 per-block counts.
__global__ __launch_bounds__(256) void scanblk_kernel(const int* __restrict__ blockhist,
                                                      int* __restrict__ blockbase,
                                                      int* __restrict__ bucket_total) {
    __shared__ int ss[256];
    int b = blockIdx.x, tid = threadIdx.x;
    int v0 = blockhist[(long)tid * NBUCK + b];
    int v1 = blockhist[(long)(tid + 256) * NBUCK + b];
    int t = v0 + v1;
    ss[tid] = t; __syncthreads();
    for (int o = 1; o < 256; o <<= 1) {
        int u = (tid >= o) ? ss[tid - o] : 0;
        __syncthreads(); ss[tid] += u; __syncthreads();
    }
    int ex = ss[tid] - t;
    blockbase[(long)tid * NBUCK + b] = ex;
    blockbase[(long)(tid + 256) * NBUCK + b] = ex + v0;
    if (tid == 255) bucket_total[b] = ss[255];
}

// A2b: exclusive scan over 196 bucket totals; also seals rowptr[N] = E.
__global__ __launch_bounds__(256) void scanbuck_kernel(const int* __restrict__ bucket_total,
                                                       int* __restrict__ bucket_base,
                                                       int* __restrict__ rowptr) {
    __shared__ int ss[256];
    int tid = threadIdx.x;
    int v = (tid < NBUCK) ? bucket_total[tid] : 0;
    ss[tid] = v; __syncthreads();
    for (int o = 1; o < 256; o <<= 1) {
        int u = (tid >= o) ? ss[tid - o] : 0;
        __syncthreads(); ss[tid] += u; __syncthreads();
    }
    if (tid < NBUCK) bucket_base[tid] = ss[tid] - v;
    if (tid == NBUCK - 1) { bucket_base[NBUCK] = ss[tid]; rowptr[N_NODES] = ss[tid]; }
}

// ---------------------------------------------------------------------------
// A3: scatter (src,dst) into bucket-grouped ebuf2 using LDS cursors.
__global__ __launch_bounds__(256) void scat_kernel(const int* __restrict__ esrc,
                                                   const int* __restrict__ edst,
                                                   const int* __restrict__ blockbase,
                                                   const int* __restrict__ bucket_base,
                                                   int2* __restrict__ ebuf2,
                                                   int chunk, int nE) {
    __shared__ int cur[NBUCK];
    int tid = threadIdx.x;
    for (int i = tid; i < NBUCK; i += 256)
        cur[i] = bucket_base[i] + blockbase[(long)blockIdx.x * NBUCK + i];
    __syncthreads();
    int e0 = blockIdx.x * chunk;
    int e1 = min(e0 + chunk, nE);
    for (int e = e0 + tid; e < e1; e += 256) {
        int s = esrc[e];
        int d = edst[e];
        int pos = atomicAdd(&cur[d >> BSH], 1);      // LDS atomic
        ebuf2[pos] = make_int2(s, d);
    }
}

// ---------------------------------------------------------------------------
// B: one block per bucket — exact local CSR via LDS counters + block scan.
// Writes rowptr, dinv, compacted ebuf. Zero global atomics.
__global__ __launch_bounds__(256) void build_kernel(const int2* __restrict__ ebuf2,
                                                    const int* __restrict__ bucket_base,
                                                    int* __restrict__ rowptr,
                                                    float* __restrict__ dinv,
                                                    int* __restrict__ ebuf) {
    __shared__ int cnt[512];
    __shared__ int off[512];
    __shared__ int ss[256];
    int b = blockIdx.x, tid = threadIdx.x;
    int base = bucket_base[b], end = bucket_base[b + 1];

    for (int i = tid; i < 512; i += 256) cnt[i] = 0;
    __syncthreads();
    for (int e = base + tid; e < end; e += 256)
        atomicAdd(&cnt[ebuf2[e].y & 511], 1);
    __syncthreads();

    int c0 = cnt[2 * tid], c1 = cnt[2 * tid + 1];
    int t = c0 + c1;
    ss[tid] = t; __syncthreads();
    for (int o = 1; o < 256; o <<= 1) {
        int u = (tid >= o) ? ss[tid - o] : 0;
        __syncthreads(); ss[tid] += u; __syncthreads();
    }
    int ex = ss[tid] - t;
    off[2 * tid] = ex; off[2 * tid + 1] = ex + c0;
    __syncthreads();

    int node0 = b << BSH;
    for (int i = tid; i < 512; i += 256) {
        int node = node0 + i;
        if (node < N_NODES) {
            rowptr[node] = base + off[i];
            dinv[node]   = rsqrtf((float)(cnt[i] + 1));
        }
    }
    for (int i = tid; i < 512; i += 256) cnt[i] = 0;   // same indices per thread: safe
    __syncthreads();
    for (int e = base + tid; e < end; e += 256) {
        int2 sd = ebuf2[e];
        int li = sd.y & 511;
        int r = atomicAdd(&cnt[li], 1);                // LDS atomic
        ebuf[base + off[li] + r] = sd.x;
    }
}

// ---------------------------------------------------------------------------
// Kc: WcT[8][256] = (W1 @ Wfc)^T  and  cvec[8] = b1 @ Wfc + bfc.
__global__ __launch_bounds__(256) void wc_kernel(const float* __restrict__ W1,
                                                 const float* __restrict__ b1,
                                                 const float* __restrict__ Wfc,
                                                 const float* __restrict__ bfc,
                                                 float* __restrict__ WcT,
                                                 float* __restrict__ cvec) {
    __shared__ float wfs[NHID * NCLASS];
    __shared__ float bs[NHID];
    int tid = threadIdx.x;
    for (int i = tid; i < NHID * NCLASS; i += 256) wfs[i] = Wfc[i];
    if (tid < NHID) bs[tid] = b1[tid];
    __syncthreads();

    float acc[NCLASS] = {};
    for (int h = 0; h < NHID; h++) {
        float w = W1[tid * NHID + h];
        #pragma unroll
        for (int c = 0; c < NCLASS; c++) acc[c] += w * wfs[h * NCLASS + c];
    }
    #pragma unroll
    for (int c = 0; c < NCLASS; c++) WcT[c * NFEAT + tid] = acc[c];

    if (tid < NCLASS) {
        float a = bfc[tid];
        for (int h = 0; h < NHID; h++) a += bs[h] * wfs[h * NCLASS + tid];
        cvec[tid] = a;
    }
}

// ---------------------------------------------------------------------------
// Kz: Zs[i][c] = dot(X[i], WcT[c]) * dinv[i].  Wave = 8 rows; 8 lanes/row
// own 32 features in 8 float4 regs; WcT in LDS; shfl_xor reduce per class.
__global__ __launch_bounds__(256) void z_kernel(const float* __restrict__ X,
                                                const float* __restrict__ WcT,
                                                const float* __restrict__ dinv,
                                                float* __restrict__ Zs, int n) {
    __shared__ float4 wlds[NCLASS * 64];
    int tid = threadIdx.x;
    #pragma unroll
    for (int i = tid; i < NCLASS * 64; i += 256)
        wlds[i] = ((const float4*)WcT)[i];
    __syncthreads();

    const int lane = tid & 63;
    const int sub  = lane & 7;
    const int rsub = lane >> 3;
    const int wid  = (blockIdx.x * 256 + tid) >> 6;
    const int nw   = (gridDim.x * 256) >> 6;
    const int ngroups = (n + 7) >> 3;

    for (int g = wid; g < ngroups; g += nw) {
        int row = g * 8 + rsub;
        bool ok = row < n;
        int r = ok ? row : (n - 1);
        const float4* xr = (const float4*)(X + (long)r * NFEAT);
        float4 xv[8];
        #pragma unroll
        for (int k = 0; k < 8; k++) xv[k] = xr[sub + 8 * k];

        float res = 0.f;
        #pragma unroll
        for (int c = 0; c < NCLASS; c++) {
            float s = 0.f;
            #pragma unroll
            for (int k = 0; k < 8; k++) {
                float4 w = wlds[c * 64 + sub + 8 * k];
                s += xv[k].x * w.x + xv[k].y * w.y + xv[k].z * w.z + xv[k].w * w.w;
            }
            s += __shfl_xor(s, 1);
            s += __shfl_xor(s, 2);
            s += __shfl_xor(s, 4);
            if (sub == c) res = s;
        }
        if (ok) Zs[(long)row * NCLASS + sub] = res * dinv[row];
    }
}

// ---------------------------------------------------------------------------
// Kg: out[d] = dinv[d]*(Zs[d] + sum_{s in CSR(d)} Zs[s]) + cvec
// Thread per (node, half-row); ebuf reads are contiguous per node.
__global__ __launch_bounds__(256) void gather_fc_kernel(const float* __restrict__ Zs,
                                                        const int* __restrict__ ebuf,
                                                        const int* __restrict__ rowptr,
                                                        const float* __restrict__ dinv,
                                                        const float* __restrict__ cvec,
                                                        float* __restrict__ out, int n) {
    int idx = blockIdx.x * 256 + threadIdx.x;
    if (idx >= 2 * n) return;
    int node = idx >> 1;
    int h    = idx & 1;
    int s0 = rowptr[node], s1 = rowptr[node + 1];
    const float4* Zs4 = (const float4*)Zs;

    float4 a = Zs4[node * 2 + h];                      // self-loop (pre-scaled)
    int k = s0;
    for (; k + 1 < s1; k += 2) {
        int i0 = ebuf[k], i1 = ebuf[k + 1];
        float4 z0 = Zs4[i0 * 2 + h];
        float4 z1 = Zs4[i1 * 2 + h];
        a.x += z0.x + z1.x; a.y += z0.y + z1.y;
        a.z += z0.z + z1.z; a.w += z0.w + z1.w;
    }
    if (k < s1) {
        float4 z = Zs4[ebuf[k] * 2 + h];
        a.x += z.x; a.y += z.y; a.z += z.z; a.w += z.w;
    }

    float dd = dinv[node];
    float4 cv = ((const float4*)cvec)[h];
    float4 o;
    o.x = a.x * dd + cv.x; o.y = a.y * dd + cv.y;
    o.z = a.z * dd + cv.z; o.w = a.w * dd + cv.w;
    ((float4*)out)[node * 2 + h] = o;
}

// ---------------------------------------------------------------------------
extern "C" void kernel_launch(void* const* d_in, const int* in_sizes, int n_in,
                              void* d_out, int out_size, void* d_ws, size_t ws_size,
                              hipStream_t stream) {
    const float* x    = (const float*)d_in[0];   // [N, 256]
    const int*   eidx = (const int*)d_in[1];     // [2, E]
    const float* W1   = (const float*)d_in[2];   // [256, 128]
    const float* b1   = (const float*)d_in[3];   // [128]
    const float* Wfc  = (const float*)d_in[4];   // [128, 8]
    const float* bfc  = (const float*)d_in[5];   // [8]
    float* out = (float*)d_out;

    const int N = N_NODES;
    const int E = in_sizes[1] / 2;
    const int chunk = (E + NBLK - 1) / NBLK;

    const int* esrc = eidx;
    const int* edst = eidx + E;

    // workspace layout (~24 MB); every region written before read, no memsets.
    float* Zs     = (float*)d_ws;                    // 8N
    float* dinv   = Zs + (long)8 * N;                // N
    int*   rowptr = (int*)(dinv + N);                // N+4 (pad)
    float* cvec   = (float*)(rowptr + N + 4);        // 8
    float* WcT    = cvec + 8;                        // 2048
    int*   btot   = (int*)(WcT + NCLASS * NFEAT);    // NBUCK
    int*   bbase  = btot + NBUCK;                    // NBUCK+1 (pad to +4)
    int*   bhist  = bbase + NBUCK + 4;               // NBLK*NBUCK
    int*   bbas2  = bhist + NBLK * NBUCK;            // NBLK*NBUCK
    // align ebuf2 to 16 B
    size_t ofs = (size_t)(bbas2 + NBLK * NBUCK - (int*)d_ws);
    ofs = (ofs + 3) & ~(size_t)3;
    int2*  ebuf2  = (int2*)((int*)d_ws + ofs);       // E int2
    int*   ebuf   = (int*)(ebuf2 + E);               // E

    wc_kernel<<<1, 256, 0, stream>>>(W1, b1, Wfc, bfc, WcT, cvec);

    hist_kernel<<<NBLK, 256, 0, stream>>>(edst, bhist, chunk, E);
    scanblk_kernel<<<NBUCK, 256, 0, stream>>>(bhist, bbas2, btot);
    scanbuck_kernel<<<1, 256, 0, stream>>>(btot, bbase, rowptr);
    scat_kernel<<<NBLK, 256, 0, stream>>>(esrc, edst, bbas2, bbase, ebuf2, chunk, E);
    build_kernel<<<NBUCK, 256, 0, stream>>>(ebuf2, bbase, rowptr, dinv, ebuf);

    z_kernel<<<1563, 256, 0, stream>>>(x, WcT, dinv, Zs, N);

    gather_fc_kernel<<<(2 * N + 255) / 256, 256, 0, stream>>>(
        Zs, ebuf, rowptr, dinv, cvec, out, N);
}